// Round 2
// baseline (651.643 us; speedup 1.0000x reference)
//
#include <hip/hip_runtime.h>

// MeanAggregator: out[b,:] = mean over {neighbours[b,0..9], nodes[b]} of features[idx,:]
// B=100000, K=10, N=1000000, D=128. Pure memory-bound random gather.
//
// Layout: 32 lanes per node, float4 per lane (32*16B = 512B = one feature row).
// 256-thread block = 8 nodes. Each wave-level VMEM instruction moves 1KB
// (two nodes' rows), 16B/lane — the coalescing sweet spot (G13). 11 independent
// row loads in flight per 32-lane group for latency hiding.

#define KNEIGH 10
#define DDIM 128

__global__ __launch_bounds__(256) void MeanAggregator_36386962932386_kernel(
    const int* __restrict__ nodes,
    const int* __restrict__ neighbours,
    const float* __restrict__ features,
    float* __restrict__ out,
    int B)
{
    const int node = blockIdx.x * 8 + (threadIdx.x >> 5);
    if (node >= B) return;
    const int c = threadIdx.x & 31;   // float4 column within the row

    // 11 row indices (per-32-lane-group uniform loads; L1/L2 broadcast, tiny).
    int idx[KNEIGH + 1];
    const long long nb = (long long)node * KNEIGH;
#pragma unroll
    for (int j = 0; j < KNEIGH; ++j) idx[j] = neighbours[nb + j];
    idx[KNEIGH] = nodes[node];

    // Issue all 11 independent 512B row loads (float4/lane), then reduce.
    float4 v[KNEIGH + 1];
#pragma unroll
    for (int j = 0; j < KNEIGH + 1; ++j) {
        v[j] = ((const float4*)(features + (long long)idx[j] * DDIM))[c];
    }

    float4 acc = v[0];
#pragma unroll
    for (int j = 1; j < KNEIGH + 1; ++j) {
        acc.x += v[j].x;
        acc.y += v[j].y;
        acc.z += v[j].z;
        acc.w += v[j].w;
    }

    const float s = 1.0f / (float)(KNEIGH + 1);
    acc.x *= s; acc.y *= s; acc.z *= s; acc.w *= s;

    ((float4*)(out + (long long)node * DDIM))[c] = acc;
}

extern "C" void kernel_launch(void* const* d_in, const int* in_sizes, int n_in,
                              void* d_out, int out_size, void* d_ws, size_t ws_size,
                              hipStream_t stream)
{
    const int* nodes      = (const int*)d_in[0];
    const int* neighbours = (const int*)d_in[1];
    const float* features = (const float*)d_in[2];
    float* out            = (float*)d_out;

    const int B = in_sizes[0];           // 100000
    const int blocks = (B + 7) / 8;      // 8 nodes per 256-thread block

    MeanAggregator_36386962932386_kernel<<<blocks, 256, 0, stream>>>(
        nodes, neighbours, features, out, B);
}